// Round 9
// baseline (696.790 us; speedup 1.0000x reference)
//
#include <hip/hip_runtime.h>

#define N_NODES 50000
#define N_EDGES 1600000
#define D_FEAT 512
#define FILTERS 256
#define NUM_CLASSES 16

typedef __bf16 bf16x8 __attribute__((ext_vector_type(8)));
typedef float f32x4 __attribute__((ext_vector_type(4)));
typedef _Float16 half4 __attribute__((ext_vector_type(4)));
typedef _Float16 f16x8 __attribute__((ext_vector_type(8)));

#define GLOAD_LDS16(g, l)                                                  \
  __builtin_amdgcn_global_load_lds(                                        \
      (const __attribute__((address_space(1))) unsigned int*)(g),          \
      (__attribute__((address_space(3))) unsigned int*)(l), 16, 0, 0)

// ---------------------------------------------------------------------------
// Split W1 [512,256] fp32 -> W1^T hi/lo bf16 [256,512]
// ---------------------------------------------------------------------------
__global__ __launch_bounds__(256) void split_w1_kernel(
    const float* __restrict__ W1, __bf16* __restrict__ Wth,
    __bf16* __restrict__ Wtl) {
  const int idx = blockIdx.x * 256 + threadIdx.x;
  const int k = idx >> 8;
  const int n = idx & 255;
  const float v = W1[idx];
  const __bf16 h = (__bf16)v;
  const __bf16 l = (__bf16)(v - (float)h);
  Wth[n * D_FEAT + k] = h;
  Wtl[n * D_FEAT + k] = l;
}

// ---------------------------------------------------------------------------
// GEMM1 via MFMA bf16x3: XW1 = X @ W1, fp32-accurate, output stored fp16.
// ---------------------------------------------------------------------------
__global__ __launch_bounds__(256) void gemm1_mfma_kernel(
    const float* __restrict__ A, const __bf16* __restrict__ Bh,
    const __bf16* __restrict__ Bl, _Float16* __restrict__ C) {
  const int K = D_FEAT;
  __shared__ __bf16 sAh[128 * 32];
  __shared__ __bf16 sAl[128 * 32];
  __shared__ __bf16 sBh[128 * 32];
  __shared__ __bf16 sBl[128 * 32];

  const int tid = threadIdx.x;
  const int wave = tid >> 6;
  const int lane = tid & 63;
  const int wm = (wave >> 1) * 64;
  const int wn = (wave & 1) * 64;
  const int m0 = blockIdx.x * 128;
  const int n0 = blockIdx.y * 128;

  const int arow = tid >> 1;
  const int aks = (tid & 1) * 16;
  int am = m0 + arow;
  if (am >= N_NODES) am = N_NODES - 1;
  const float* aptr = A + (size_t)am * K + aks;

  const int lr = lane >> 2;
  const int lc = (lane & 3) * 8;
  const int fm = lane & 15;
  const int fq = lane >> 4;

  f32x4 acc[4][4] = {};

  for (int k0 = 0; k0 < K; k0 += 32) {
    const float4* ap = (const float4*)(aptr + k0);
    const float4 a0 = ap[0], a1 = ap[1], a2 = ap[2], a3 = ap[3];

    __syncthreads();

#pragma unroll
    for (int i = 0; i < 2; ++i) {
      const int row = wave * 32 + i * 16;
      GLOAD_LDS16(Bh + (size_t)(n0 + row + lr) * K + k0 + lc, sBh + row * 32);
      GLOAD_LDS16(Bl + (size_t)(n0 + row + lr) * K + k0 + lc, sBl + row * 32);
    }

    float va[16] = {a0.x, a0.y, a0.z, a0.w, a1.x, a1.y, a1.z, a1.w,
                    a2.x, a2.y, a2.z, a2.w, a3.x, a3.y, a3.z, a3.w};
    __bf16 hh[16], ll[16];
#pragma unroll
    for (int i = 0; i < 16; ++i) {
      const __bf16 h = (__bf16)va[i];
      hh[i] = h;
      ll[i] = (__bf16)(va[i] - (float)h);
    }
    *(bf16x8*)(sAh + arow * 32 + aks) = *(bf16x8*)&hh[0];
    *(bf16x8*)(sAh + arow * 32 + aks + 8) = *(bf16x8*)&hh[8];
    *(bf16x8*)(sAl + arow * 32 + aks) = *(bf16x8*)&ll[0];
    *(bf16x8*)(sAl + arow * 32 + aks + 8) = *(bf16x8*)&ll[8];

    __syncthreads();

    bf16x8 fah[4], fal[4], fbh[4], fbl[4];
#pragma unroll
    for (int t = 0; t < 4; ++t) {
      const int moff = (wm + t * 16 + fm) * 32 + fq * 8;
      fah[t] = *(const bf16x8*)(sAh + moff);
      fal[t] = *(const bf16x8*)(sAl + moff);
      const int noff = (wn + t * 16 + fm) * 32 + fq * 8;
      fbh[t] = *(const bf16x8*)(sBh + noff);
      fbl[t] = *(const bf16x8*)(sBl + noff);
    }
#pragma unroll
    for (int i = 0; i < 4; ++i)
#pragma unroll
      for (int j = 0; j < 4; ++j)
        acc[i][j] = __builtin_amdgcn_mfma_f32_16x16x32_bf16(fah[i], fbh[j],
                                                            acc[i][j], 0, 0, 0);
#pragma unroll
    for (int i = 0; i < 4; ++i)
#pragma unroll
      for (int j = 0; j < 4; ++j)
        acc[i][j] = __builtin_amdgcn_mfma_f32_16x16x32_bf16(fah[i], fbl[j],
                                                            acc[i][j], 0, 0, 0);
#pragma unroll
    for (int i = 0; i < 4; ++i)
#pragma unroll
      for (int j = 0; j < 4; ++j)
        acc[i][j] = __builtin_amdgcn_mfma_f32_16x16x32_bf16(fal[i], fbh[j],
                                                            acc[i][j], 0, 0, 0);
  }

#pragma unroll
  for (int ti = 0; ti < 4; ++ti) {
#pragma unroll
    for (int r = 0; r < 4; ++r) {
      const int m = m0 + wm + ti * 16 + fq * 4 + r;
      if (m < N_NODES) {
#pragma unroll
        for (int tj = 0; tj < 4; ++tj) {
          const int n = n0 + wn + tj * 16 + fm;
          C[(size_t)m * FILTERS + n] = (_Float16)acc[ti][tj][r];
        }
      }
    }
  }
}

// ---------------------------------------------------------------------------
// CSR build
// ---------------------------------------------------------------------------
__global__ __launch_bounds__(256) void hist_kernel(const int* __restrict__ edst,
                                                   int* __restrict__ deg) {
  const int e = blockIdx.x * 256 + threadIdx.x;
  if (e < N_EDGES) atomicAdd(&deg[edst[e]], 1);
}

#define SCAN_NB 196
__global__ __launch_bounds__(256) void scan_blocks_kernel(
    const int* __restrict__ deg, int* __restrict__ row_ptr,
    int* __restrict__ bsum) {
  __shared__ int s[256];
  const int i = blockIdx.x * 256 + threadIdx.x;
  const int v = (i < N_NODES) ? deg[i] : 0;
  s[threadIdx.x] = v;
  __syncthreads();
  for (int off = 1; off < 256; off <<= 1) {
    const int t = (threadIdx.x >= off) ? s[threadIdx.x - off] : 0;
    __syncthreads();
    s[threadIdx.x] += t;
    __syncthreads();
  }
  if (i < N_NODES) row_ptr[i] = s[threadIdx.x] - v;
  if (threadIdx.x == 255) bsum[blockIdx.x] = s[255];
}

__global__ __launch_bounds__(256) void scan_sums_kernel(int* __restrict__ bsum) {
  __shared__ int s[256];
  const int v = (threadIdx.x < SCAN_NB) ? bsum[threadIdx.x] : 0;
  s[threadIdx.x] = v;
  __syncthreads();
  for (int off = 1; off < 256; off <<= 1) {
    const int t = (threadIdx.x >= off) ? s[threadIdx.x - off] : 0;
    __syncthreads();
    s[threadIdx.x] += t;
    __syncthreads();
  }
  if (threadIdx.x < SCAN_NB) bsum[threadIdx.x] = s[threadIdx.x] - v;
}

__global__ __launch_bounds__(256) void scan_add_kernel(
    int* __restrict__ row_ptr, const int* __restrict__ bsum,
    int* __restrict__ cursor) {
  const int i = blockIdx.x * 256 + threadIdx.x;
  if (i < N_NODES) {
    const int r = row_ptr[i] + bsum[blockIdx.x];
    row_ptr[i] = r;
    cursor[i] = r;
  }
  if (i == 0) row_ptr[N_NODES] = N_EDGES;
}

// Fill: dst-sorted meta = (src, w_bits) + dst-local (dst & 15, tiles are
// 16-aligned) in a parallel uint16 array.
__global__ __launch_bounds__(256) void fill_kernel(
    const int* __restrict__ esrc, const int* __restrict__ edst,
    const float* __restrict__ ew, int* __restrict__ cursor,
    int2* __restrict__ meta, unsigned short* __restrict__ dloc) {
  const int e = blockIdx.x * 256 + threadIdx.x;
  if (e >= N_EDGES) return;
  const int d = edst[e];
  const int pos = atomicAdd(&cursor[d], 1);
  meta[pos] = make_int2(esrc[e], __float_as_int(ew[e]));
  dloc[pos] = (unsigned short)(d & 15);
}

// ---------------------------------------------------------------------------
// Fused gather1 + relu + gemm2 (r4 structure; best measured). Changes:
// nontemporal row loads (L1 bypass) + 1-ahead meta software pipeline.
// ---------------------------------------------------------------------------
__global__ __launch_bounds__(256) void gather1_gemm2_kernel(
    const _Float16* __restrict__ xw1, const int* __restrict__ row_ptr,
    const int2* __restrict__ meta, const float* __restrict__ W2,
    _Float16* __restrict__ h2) {
  __shared__ float red[4][16][17];
  const int wave = threadIdx.x >> 6;
  const int lane = threadIdx.x & 63;
  const int node = blockIdx.x * 4 + wave;
  const int beg = row_ptr[node];
  const int end = row_ptr[node + 1];

  float acc[4] = {};
  if (beg < end) {
    int2 m = meta[beg];
    for (int j = beg; j < end; ++j) {
      const int2 mn = (j + 1 < end) ? meta[j + 1] : m;  // prefetch next meta
      const float w = __int_as_float(m.y);
      const half4 v = __builtin_nontemporal_load(
          (const half4*)(xw1 + (size_t)m.x * FILTERS) + lane);
#pragma unroll
      for (int i = 0; i < 4; ++i) acc[i] = fmaf(w, (float)v[i], acc[i]);
      m = mn;
    }
  }

  float r[4];
#pragma unroll
  for (int i = 0; i < 4; ++i) r[i] = fmaxf(acc[i], 0.f);

  // gemm2 partials: lane's k = lane*4 + j
  float p[16] = {};
#pragma unroll
  for (int j = 0; j < 4; ++j) {
    const float4* wr =
        (const float4*)(W2 + (size_t)(lane * 4 + j) * NUM_CLASSES);
#pragma unroll
    for (int c4 = 0; c4 < 4; ++c4) {
      const float4 wv = wr[c4];
      p[c4 * 4 + 0] = fmaf(r[j], wv.x, p[c4 * 4 + 0]);
      p[c4 * 4 + 1] = fmaf(r[j], wv.y, p[c4 * 4 + 1]);
      p[c4 * 4 + 2] = fmaf(r[j], wv.z, p[c4 * 4 + 2]);
      p[c4 * 4 + 3] = fmaf(r[j], wv.w, p[c4 * 4 + 3]);
    }
  }

#pragma unroll
  for (int off = 32; off >= 16; off >>= 1)
#pragma unroll
    for (int i = 0; i < 16; ++i) p[i] += __shfl_xor(p[i], off, 64);

  if (lane < 16) {
#pragma unroll
    for (int i = 0; i < 16; ++i) red[wave][lane][i] = p[i];
  }
  if (lane < 16) {
    float sum = 0.f;
#pragma unroll
    for (int i = 0; i < 16; ++i) sum += red[wave][i][lane];
    h2[(size_t)node * NUM_CLASSES + lane] = (_Float16)sum;
  }
}

// ---------------------------------------------------------------------------
// Gather2 + softmax via MFMA (r8 structure, int2 meta + dloc + nt loads).
// ---------------------------------------------------------------------------
__global__ __launch_bounds__(256) void gather2_mfma_kernel(
    const _Float16* __restrict__ h2, const int* __restrict__ row_ptr,
    const int2* __restrict__ meta, const unsigned short* __restrict__ dloc,
    float* __restrict__ out) {
  __shared__ _Float16 lds[4][16][40];
  const int wave = threadIdx.x >> 6;
  const int lane = threadIdx.x & 63;
  const int tile = blockIdx.x * 4 + wave;
  if (tile >= N_NODES / 16) return;
  const int t0 = tile * 16;
  const int beg = row_ptr[t0];
  const int end = row_ptr[t0 + 16];

  const int cls = lane & 15;
  const int kq = lane >> 4;
  const int erow = lane >> 1;
  const int part = lane & 1;

  f32x4 acc = {0.f, 0.f, 0.f, 0.f};
  _Float16* myl = &lds[wave][0][0];

  for (int c0 = beg; c0 < end; c0 += 32) {
    int2 m = make_int2(0, 0);
    int dl = -1;
    if (lane < 32) {
      const int e = c0 + lane;
      if (e < end) {
        m = meta[e];
        dl = dloc[e];
      }
    }

    // A-frag: Sel[m=dst-local][k=edge] = w_e * (dst_e == m)
    f16x8 afrag;
#pragma unroll
    for (int j = 0; j < 8; ++j) {
      const int ei = kq * 8 + j;
      const int de = __shfl(dl, ei, 64);
      const float we = __int_as_float(__shfl(m.y, ei, 64));
      afrag[j] = (de == cls) ? (_Float16)we : (_Float16)0.f;
    }

    // stage 32 rows: lane = (edge erow, classes part*8..+8)
    const int se = __shfl(m.x, erow, 64);
    const f16x8 rv = __builtin_nontemporal_load(
        (const f16x8*)(h2 + (size_t)se * NUM_CLASSES + part * 8));
#pragma unroll
    for (int j = 0; j < 8; ++j) myl[(part * 8 + j) * 40 + erow] = rv[j];

    const f16x8 bfrag = *(const f16x8*)(myl + cls * 40 + kq * 8);

    acc = __builtin_amdgcn_mfma_f32_16x16x32_f16(afrag, bfrag, acc, 0, 0, 0);
  }

#pragma unroll
  for (int r = 0; r < 4; ++r) {
    const float a = acc[r];
    float mx = a;
#pragma unroll
    for (int off = 8; off >= 1; off >>= 1)
      mx = fmaxf(mx, __shfl_xor(mx, off, 16));
    const float ex = __expf(a - mx);
    float sm = ex;
#pragma unroll
    for (int off = 8; off >= 1; off >>= 1) sm += __shfl_xor(sm, off, 16);
    out[(size_t)(t0 + kq * 4 + r) * NUM_CLASSES + cls] = ex / sm;
  }
}

extern "C" void kernel_launch(void* const* d_in, const int* in_sizes, int n_in,
                              void* d_out, int out_size, void* d_ws,
                              size_t ws_size, hipStream_t stream) {
  const float* x = (const float*)d_in[0];
  const float* W1 = (const float*)d_in[1];
  const float* W2 = (const float*)d_in[2];
  const float* ew = (const float*)d_in[3];
  const int* esrc = (const int*)d_in[4];
  const int* edst = (const int*)d_in[5];
  float* out = (float*)d_out;

  _Float16* xw1 = (_Float16*)d_ws;                            // 25.6 MB
  _Float16* h2 = xw1 + (size_t)N_NODES * FILTERS;             // 1.6 MB
  int* row_ptr = (int*)(h2 + (size_t)N_NODES * NUM_CLASSES);  // 50001
  int* cursor = row_ptr + (N_NODES + 1);
  int* deg = cursor + N_NODES;
  int2* meta = (int2*)(((uintptr_t)(deg + N_NODES) + 15) & ~(uintptr_t)15);
  unsigned short* dloc = (unsigned short*)(meta + N_EDGES);  // 3.2 MB
  __bf16* w1th = (__bf16*)(((uintptr_t)(dloc + N_EDGES) + 15) & ~(uintptr_t)15);
  __bf16* w1tl = w1th + D_FEAT * FILTERS;
  int* bsum = (int*)(w1tl + D_FEAT * FILTERS);

  hipMemsetAsync(deg, 0, N_NODES * sizeof(int), stream);
  hist_kernel<<<(N_EDGES + 255) / 256, 256, 0, stream>>>(edst, deg);
  scan_blocks_kernel<<<SCAN_NB, 256, 0, stream>>>(deg, row_ptr, bsum);
  scan_sums_kernel<<<1, 256, 0, stream>>>(bsum);
  scan_add_kernel<<<SCAN_NB, 256, 0, stream>>>(row_ptr, bsum, cursor);
  fill_kernel<<<(N_EDGES + 255) / 256, 256, 0, stream>>>(esrc, edst, ew,
                                                         cursor, meta, dloc);

  split_w1_kernel<<<(D_FEAT * FILTERS) / 256, 256, 0, stream>>>(W1, w1th, w1tl);
  dim3 g1((N_NODES + 127) / 128, FILTERS / 128);
  gemm1_mfma_kernel<<<g1, 256, 0, stream>>>(x, w1th, w1tl, xw1);

  gather1_gemm2_kernel<<<N_NODES / 4, 256, 0, stream>>>(xw1, row_ptr, meta, W2,
                                                        h2);

  gather2_mfma_kernel<<<(N_NODES / 16 + 3) / 4, 256, 0, stream>>>(
      h2, row_ptr, meta, dloc, out);
}